// Round 7
// baseline (165.913 us; speedup 1.0000x reference)
//
#include <hip/hip_runtime.h>
#include <hip/hip_bf16.h>
#include <math.h>

// Problem constants (BN, N, FIN, FO, H) from the reference
#define BN_   4
#define NN_   2048
#define FIN_  128
#define FO_   64
#define H_    4
#define D_    256   // FO*H

typedef __attribute__((ext_vector_type(8))) short bf16x8;   // 8 bf16 = 4 VGPRs
typedef __attribute__((ext_vector_type(4))) float floatx4;  // MFMA C/D frag

#define LOG2E 1.4426950408889634f

#if __has_builtin(__builtin_amdgcn_exp2f)
#define EXP2(x) __builtin_amdgcn_exp2f(x)
#else
#define EXP2(x) exp2f(x)
#endif

__device__ __forceinline__ float bf2f(short u) {
    union { unsigned int i; float f; } v;
    v.i = ((unsigned int)(unsigned short)u) << 16;
    return v.f;
}
__device__ __forceinline__ short f2bf(float f) {
    union { float f; unsigned int u; } v; v.f = f;
    unsigned int r = v.u + 0x7fffu + ((v.u >> 16) & 1u);  // RNE
    return (short)(unsigned short)(r >> 16);
}

// pack two floats to two bf16 (RNE) in one dword; elem0 in low 16 bits
#if defined(__BF16_MANT_DIG__)
typedef __bf16 bfr2 __attribute__((ext_vector_type(2)));
__device__ __forceinline__ unsigned int pack_bf16(float a, float b) {
    union { bfr2 h; unsigned int u; } v;
    v.h = (bfr2){(__bf16)a, (__bf16)b};
    return v.u;
}
#else
__device__ __forceinline__ unsigned int pack_bf16(float a, float b) {
    return ((unsigned int)(unsigned short)f2bf(a)) |
           (((unsigned int)(unsigned short)f2bf(b)) << 16);
}
#endif

// load 8 consecutive fp32 and round to a bf16x8 MFMA fragment
__device__ __forceinline__ bf16x8 load8f(const float* __restrict__ p) {
    floatx4 a = *(const floatx4*)p;
    floatx4 b = *(const floatx4*)(p + 4);
    union { bf16x8 v; unsigned int u[4]; } r;
    r.u[0] = pack_bf16(a[0], a[1]);
    r.u[1] = pack_bf16(a[2], a[3]);
    r.u[2] = pack_bf16(b[0], b[1]);
    r.u[3] = pack_bf16(b[2], b[3]);
    return r.v;
}

// attention score -> exp weight (bit-identical across rounds)
__device__ __forceinline__ float score_exp(float ssv, float stv, float av) {
    float s = ssv + stv;
    s = fmaxf(s, 0.2f * s);            // leaky_relu(0.2)
    return EXP2((s + av) * LOG2E);
}

// ---------------------------------------------------------------------------
// Kernel 1: projection -> PT2 (fragment-tiled bf16) + s_src/s_tgt.
//
// Round-7 change (attn kernel untouched): round-6 made attn loads dense but
// left proj with (a) a 2-byte scatter PT2 store (the same transaction
// pathology round 6 removed from attn) and (b) a 64-block grid (1/4 GPU).
// Fix: j-tile 256->64 per block (grid 32x4xcnt = 256 blocks, full GPU) and
// store via an LDS [64f][72j] transpose tile so every PT2 global store is a
// dense 16B/lane (1 KB/wave) write. PT2 layout is IDENTICAL to round 6:
//   elem(h, f, j) -> ((b_rel*H + h)*64 + (j>>5))*2048
//                    + (f>>4)*512 + ((j>>3)&3)*128 + (f&15)*8 + (j&7)
// ---------------------------------------------------------------------------
__global__ __launch_bounds__(256) void proj_kernel(
    const float* __restrict__ x,      // (BN, NN, FIN) fp32
    const float* __restrict__ wproj,  // (D, FIN) fp32
    const float* __restrict__ ssrc,   // (H, FO) fp32
    const float* __restrict__ stgt,   // (H, FO) fp32
    short* __restrict__ pt,           // (nb) PT2 slabs, 1 MiB each
    float* __restrict__ sS,           // (nb*H, NN) fp32
    float* __restrict__ sT,           // (nb*H, NN) fp32
    int b0)
{
    __shared__ short ptl[64][72];     // [f][j] bf16 tile, +8 pad (9216 B)

    const int tid  = threadIdx.x;
    const int wave = tid >> 6;
    const int lane = tid & 63;
    const int l16  = lane & 15;
    const int quad = lane >> 4;

    const int b_rel = blockIdx.z;
    const int b  = b0 + b_rel;
    const int h  = blockIdx.y;            // head
    const int j0 = blockIdx.x * 64 + wave * 16;   // this wave's 16 j-rows

    floatx4 acc[4];                   // [mi] : 64 f x 16 j
#pragma unroll
    for (int mi = 0; mi < 4; ++mi)
        acc[mi] = (floatx4){0.f, 0.f, 0.f, 0.f};

#pragma unroll
    for (int kc = 0; kc < 4; ++kc) {
        const int c = kc * 32 + quad * 8;
        bf16x8 afr[4];
#pragma unroll
        for (int mi = 0; mi < 4; ++mi) {
            int f = mi * 16 + l16;                // f within head
            int srow = f * H_ + h;                // W_proj row (flat d = f*H+h)
            afr[mi] = load8f(wproj + srow * FIN_ + c);
        }
        bf16x8 bfr = load8f(x + ((size_t)b * NN_ + j0 + l16) * FIN_ + c);
#pragma unroll
        for (int mi = 0; mi < 4; ++mi)
            acc[mi] = __builtin_amdgcn_mfma_f32_16x16x32_bf16(
                afr[mi], bfr, acc[mi], 0, 0, 0);
    }

    // ---- stage C-fragments into the [f][j] LDS tile ----
    // lane holds (f = mi*16 + quad*4 + r, j_local = wave*16 + l16)
#pragma unroll
    for (int mi = 0; mi < 4; ++mi)
#pragma unroll
        for (int r = 0; r < 4; ++r)
            ptl[mi * 16 + quad * 4 + r][wave * 16 + l16] = f2bf(acc[mi][r]);

    // ---- score dot-products from fp32 accumulators (register-local) ----
    float wsv[4][4], wtv[4][4];
#pragma unroll
    for (int mi = 0; mi < 4; ++mi)
#pragma unroll
        for (int r = 0; r < 4; ++r) {
            int f = mi * 16 + quad * 4 + r;
            wsv[mi][r] = ssrc[h * FO_ + f];
            wtv[mi][r] = stgt[h * FO_ + f];
        }
    {
        float ps = 0.f, pg = 0.f;
#pragma unroll
        for (int mi = 0; mi < 4; ++mi)
#pragma unroll
            for (int r = 0; r < 4; ++r) {
                ps = fmaf(wsv[mi][r], acc[mi][r], ps);
                pg = fmaf(wtv[mi][r], acc[mi][r], pg);
            }
        ps += __shfl_xor(ps, 16, 64); ps += __shfl_xor(ps, 32, 64);
        pg += __shfl_xor(pg, 16, 64); pg += __shfl_xor(pg, 32, 64);
        if (quad == 0) {
            const size_t sbase = ((size_t)b_rel * H_ + h) * NN_;
            sS[sbase + j0 + l16] = ps;
            sT[sbase + j0 + l16] = pg;
        }
    }

    __syncthreads();

    // ---- dense PT2 store: 512 units of 16B, 2 per thread ----
    const size_t hbase = ((size_t)b_rel * H_ + h) * (size_t)(64 * 2048);
#pragma unroll
    for (int p = 0; p < 2; ++p) {
        const int uid = p * 256 + tid;            // 0..511
        const int tl  = (uid >> 8) & 1;           // tile within block (2x32 j)
        const int mi  = (uid >> 6) & 3;           // f-block
        const int l   = uid & 63;                 // = jsub*16 + f15
        const int f   = mi * 16 + (l & 15);
        const int js  = tl * 32 + (l >> 4) * 8;   // j_local of 8-run
        bf16x8 v = *(const bf16x8*)&ptl[f][js];   // 16B-aligned (72|8, js|8)
        const int tile_glob = blockIdx.x * 2 + tl;
        *(bf16x8*)&pt[hbase + (size_t)tile_glob * 2048 + mi * 512
                      + (size_t)l * 8] = v;       // dense: lane*16B
    }
}

// ---------------------------------------------------------------------------
// Kernel 2: fused attention, 4 heads per block, i-tile = 16.
// UNCHANGED from round 6 (54.5 us, verified): all main-loop global loads
// dense; adj staged via wave-private LDS tile with T14 issue-early/
// write-late split; PT B-fragments read from PT2 as uniform_base + lane*16.
// ---------------------------------------------------------------------------
#define RSTRIDE 65   // LDS row stride (pad +1 col to break bank alignment)
#define WSLOT   (RSTRIDE * 16 + 16)   // 1056 floats per wave slot

__global__ __launch_bounds__(512, 2) void attn_kernel(
    const float* __restrict__ adj,    // (BN, NN, NN) fp32
    const short* __restrict__ pt,     // PT2 slabs (see proj_kernel)
    const float* __restrict__ sS,     // (nb*H, NN) fp32
    const float* __restrict__ sT,     // (nb*H, NN) fp32
    const float* __restrict__ bias,   // (D,) fp32
    float* __restrict__ out,          // (BN, NN, D) fp32
    int b0)
{
    __shared__ union {
        struct {
            float adjs[8][16][36];    // per-wave adj tile (18432 B)
            float st[8][4][256];      // per-wave s_tgt slices (32768 B)
        } m;
        float red[8][WSLOT];          // cross-wave reduction (33792 B)
    } sm;

    const int tid  = threadIdx.x;
    const int w    = tid >> 6;        // wave = 256-wide j-slice
    const int lane = tid & 63;
    const int l16  = lane & 15;
    const int quad = lane >> 4;
    const int r8   = lane >> 3;       // 0..7  (adj stage row-in-group)
    const int c4   = (lane & 7) * 4;  // 0,4..28 (adj stage col, floats)

    const int b_rel = blockIdx.z;
    const int b  = b0 + b_rel;
    const int i0 = blockIdx.x * 16;

    const short* pt2_b = pt + (size_t)b_rel * H_ * (size_t)(64 * 2048);
    const size_t sb = (size_t)b_rel * H_ * NN_;

    // stage s_tgt slices for all 4 heads (wave-private; no barrier needed)
    {
        const int t = lane * 4;
#pragma unroll
        for (int h = 0; h < 4; ++h)
            *(floatx4*)&sm.m.st[w][h][t] =
                *(const floatx4*)&sT[sb + (size_t)h * NN_ + w * 256 + t];
    }

    // per-lane s_src for my i-row (row = l16), all heads
    float ssv[4];
#pragma unroll
    for (int h = 0; h < 4; ++h)
        ssv[h] = sS[sb + (size_t)h * NN_ + i0 + l16];

    // adj stage base: rows i0.., cols w*256..
    const float* adj_base = adj + ((size_t)b * NN_ + i0) * NN_ + w * 256;

    floatx4 acc[4][4];                // [head][f-block], 64 regs
#pragma unroll
    for (int h = 0; h < 4; ++h)
#pragma unroll
        for (int K = 0; K < 4; ++K)
            acc[h][K] = (floatx4){0.f, 0.f, 0.f, 0.f};
    float ls[4] = {0.f, 0.f, 0.f, 0.f};

    // prologue: dense-load + stage adj tile jt=0
    floatx4 areg0 = *(const floatx4*)(adj_base + (size_t)r8 * NN_ + c4);
    floatx4 areg1 = *(const floatx4*)(adj_base + (size_t)(8 + r8) * NN_ + c4);
    *(floatx4*)&sm.m.adjs[w][r8][c4]     = areg0;
    *(floatx4*)&sm.m.adjs[w][8 + r8][c4] = areg1;

    const int lo8 = lane * 8;         // PT2 per-lane element offset

#pragma unroll
    for (int jt = 0; jt < 8; ++jt) {              // 8 iters x 32 j per wave
        const int o  = jt * 32;                   // static element offset
        const int qo = quad * 8;

        // T14 issue-early: dense global loads for the NEXT adj tile
        if (jt < 7) {
            areg0 = *(const floatx4*)(adj_base + (size_t)r8 * NN_ + o + 32 + c4);
            areg1 = *(const floatx4*)(adj_base + (size_t)(8 + r8) * NN_ + o + 32 + c4);
        }

        // A-values for this tile from LDS (wave-private, already staged)
        floatx4 ajA = *(const floatx4*)&sm.m.adjs[w][l16][qo];
        floatx4 ajB = *(const floatx4*)&sm.m.adjs[w][l16][qo + 4];

#pragma unroll
        for (int u = 0; u < 4; ++u) {
            // dense 1 KB fragment loads from PT2 (uniform base + lane*16B)
            const short* fb = pt2_b + ((size_t)u * 64 + (w * 8 + jt)) * 2048 + lo8;
            bf16x8 bfr[4];
#pragma unroll
            for (int K = 0; K < 4; ++K)
                bfr[K] = *(const bf16x8*)(fb + K * 512);

            const float* stp = &sm.m.st[w][u][qo];
            floatx4 stA = *(const floatx4*)(stp + o);
            floatx4 stB = *(const floatx4*)(stp + o + 4);

            float w0 = score_exp(ssv[u], stA[0], ajA[0]);
            float w1 = score_exp(ssv[u], stA[1], ajA[1]);
            float w2 = score_exp(ssv[u], stA[2], ajA[2]);
            float w3 = score_exp(ssv[u], stA[3], ajA[3]);
            float w4 = score_exp(ssv[u], stB[0], ajB[0]);
            float w5 = score_exp(ssv[u], stB[1], ajB[1]);
            float w6 = score_exp(ssv[u], stB[2], ajB[2]);
            float w7 = score_exp(ssv[u], stB[3], ajB[3]);
            ls[u] += ((w0 + w1) + (w2 + w3)) + ((w4 + w5) + (w6 + w7));
            union { bf16x8 v; unsigned int u4[4]; } a0;
            a0.u4[0] = pack_bf16(w0, w1);
            a0.u4[1] = pack_bf16(w2, w3);
            a0.u4[2] = pack_bf16(w4, w5);
            a0.u4[3] = pack_bf16(w6, w7);
#pragma unroll
            for (int K = 0; K < 4; ++K)
                acc[u][K] = __builtin_amdgcn_mfma_f32_16x16x32_bf16(
                    a0.v, bfr[K], acc[u][K], 0, 0, 0);
        }

        // T14 write-late: stage next tile after this tile's LDS reads
        if (jt < 7) {
            *(floatx4*)&sm.m.adjs[w][r8][c4]     = areg0;
            *(floatx4*)&sm.m.adjs[w][8 + r8][c4] = areg1;
        }
    }

    // wave-local row-sums over quads (row = l16 in A-layout)
#pragma unroll
    for (int h = 0; h < 4; ++h) {
        ls[h] += __shfl_xor(ls[h], 16, 64);
        ls[h] += __shfl_xor(ls[h], 32, 64);
    }

    // epilogue: 4 head-chunks of 16 rows; 8-wave LDS reduction per chunk
#pragma unroll
    for (int h = 0; h < 4; ++h) {
        __syncthreads();   // h=0: all main-loop LDS reads done; h>0: prev chunk
#pragma unroll
        for (int K = 0; K < 4; ++K)
#pragma unroll
            for (int r = 0; r < 4; ++r)
                sm.red[w][(quad * 4 + r) * RSTRIDE + K * 16 + l16] = acc[h][K][r];
        if (quad == 0)
            sm.red[w][16 * RSTRIDE + l16] = ls[h];
        __syncthreads();
#pragma unroll
        for (int p = 0; p < 2; ++p) {
            int e   = tid + p * 512;
            int row = e >> 6;
            int col = e & 63;
            float s = 0.f, l = 0.f;
#pragma unroll
            for (int ww = 0; ww < 8; ++ww) {
                s += sm.red[ww][row * RSTRIDE + col];
                l += sm.red[ww][16 * RSTRIDE + row];
            }
            float v = s / l + bias[h * FO_ + col];
            v = (v > 0.f) ? v : expm1f(v);        // elu (fp32 out)
            out[((size_t)b * NN_ + i0 + row) * D_ + h * FO_ + col] = v;
        }
    }
}

// ---------------------------------------------------------------------------
extern "C" void kernel_launch(void* const* d_in, const int* in_sizes, int n_in,
                              void* d_out, int out_size, void* d_ws, size_t ws_size,
                              hipStream_t stream) {
    const float* x     = (const float*)d_in[0];   // (4,2048,128) fp32
    const float* adj   = (const float*)d_in[1];   // (4,2048,2048) fp32
    const float* wproj = (const float*)d_in[2];   // (256,128) fp32
    const float* ssrc  = (const float*)d_in[3];   // (4,64) fp32
    const float* stgt  = (const float*)d_in[4];   // (4,64) fp32
    const float* bias  = (const float*)d_in[5];   // (256,) fp32
    float* out = (float*)d_out;                   // (4,2048,256) fp32

    // ws layout per batch: PT2 slab (1 MiB) + s_src/s_tgt (64 KiB)
    const size_t SLAB  = (size_t)D_ * NN_ * 2;          // bf16 PT2
    const size_t SSLAB = (size_t)2 * H_ * NN_ * 4;      // fp32 sS+sT
    int nb = (int)(ws_size / (SLAB + SSLAB));
    if (nb < 1) nb = 1;
    if (nb > 4) nb = 4;

    short* pt = (short*)d_ws;
    float* sv = (float*)((char*)d_ws + (size_t)nb * SLAB);
    float* sS = sv;
    float* sT = sv + (size_t)nb * H_ * NN_;

    for (int bb0 = 0; bb0 < BN_; bb0 += nb) {
        int cnt = (BN_ - bb0 < nb) ? (BN_ - bb0) : nb;
        proj_kernel<<<dim3(NN_ / 64, H_, cnt), 256, 0, stream>>>(
            x, wproj, ssrc, stgt, pt, sS, sT, bb0);
        attn_kernel<<<dim3(NN_ / 16, 1, cnt), 512, 0, stream>>>(
            adj, pt, sS, sT, bias, out, bb0);
    }
}

// Round 8
// 161.052 us; speedup vs baseline: 1.0302x; 1.0302x over previous
//
#include <hip/hip_runtime.h>
#include <hip/hip_bf16.h>
#include <math.h>

// Problem constants (BN, N, FIN, FO, H) from the reference
#define BN_   4
#define NN_   2048
#define FIN_  128
#define FO_   64
#define H_    4
#define D_    256   // FO*H

typedef __attribute__((ext_vector_type(8))) short bf16x8;   // 8 bf16 = 4 VGPRs
typedef __attribute__((ext_vector_type(4))) float floatx4;  // MFMA C/D frag

#define LOG2E 1.4426950408889634f

#if __has_builtin(__builtin_amdgcn_exp2f)
#define EXP2(x) __builtin_amdgcn_exp2f(x)
#else
#define EXP2(x) exp2f(x)
#endif

__device__ __forceinline__ float bf2f(short u) {
    union { unsigned int i; float f; } v;
    v.i = ((unsigned int)(unsigned short)u) << 16;
    return v.f;
}
__device__ __forceinline__ short f2bf(float f) {
    union { float f; unsigned int u; } v; v.f = f;
    unsigned int r = v.u + 0x7fffu + ((v.u >> 16) & 1u);  // RNE
    return (short)(unsigned short)(r >> 16);
}

// pack two floats to two bf16 (RNE) in one dword; elem0 in low 16 bits
#if defined(__BF16_MANT_DIG__)
typedef __bf16 bfr2 __attribute__((ext_vector_type(2)));
__device__ __forceinline__ unsigned int pack_bf16(float a, float b) {
    union { bfr2 h; unsigned int u; } v;
    v.h = (bfr2){(__bf16)a, (__bf16)b};
    return v.u;
}
#else
__device__ __forceinline__ unsigned int pack_bf16(float a, float b) {
    return ((unsigned int)(unsigned short)f2bf(a)) |
           (((unsigned int)(unsigned short)f2bf(b)) << 16);
}
#endif

// load 8 consecutive fp32 and round to a bf16x8 MFMA fragment
__device__ __forceinline__ bf16x8 load8f(const float* __restrict__ p) {
    floatx4 a = *(const floatx4*)p;
    floatx4 b = *(const floatx4*)(p + 4);
    union { bf16x8 v; unsigned int u[4]; } r;
    r.u[0] = pack_bf16(a[0], a[1]);
    r.u[1] = pack_bf16(a[2], a[3]);
    r.u[2] = pack_bf16(b[0], b[1]);
    r.u[3] = pack_bf16(b[2], b[3]);
    return r.v;
}

// attention score -> exp weight (bit-identical across rounds)
__device__ __forceinline__ float score_exp(float ssv, float stv, float av) {
    float s = ssv + stv;
    s = fmaxf(s, 0.2f * s);            // leaky_relu(0.2)
    return EXP2((s + av) * LOG2E);
}

// ---------------------------------------------------------------------------
// Kernel 1: projection -> PT2 (fragment-tiled bf16) + s_src/s_tgt.
//
// Round-8: combine the two proven-good halves.
//  * Main loop = round-2's exact shape (j-tile 256/block, wave does 64 j x
//    64 f, acc[4][4], 8 independent 16B loads per kc) -- measured fast
//    (proj ~9-16 us) in rounds 0-4. Round-7's 64-j tile (5 loads/kc, 1
//    wave/SIMD) was latency-exposed: neutral vs round-6's scatter store.
//  * Store = round-7's dense path, scaled up: all C-fragments go through an
//    LDS [64f][264j] transpose tile; the block then emits its PT2 range
//    (8 tiles x 2048 shorts = 32 KB, CONTIGUOUS in PT2) as 8 x 1 KB dense
//    wave-stores (lane*16B). ~2-way LDS bank aliasing on read/write = free.
// PT2 layout (IDENTICAL to rounds 6/7, attn kernel untouched):
//   elem(h, f, j) -> ((b_rel*H + h)*64 + (j>>5))*2048
//                    + (f>>4)*512 + ((j>>3)&3)*128 + (f&15)*8 + (j&7)
// ---------------------------------------------------------------------------
__global__ __launch_bounds__(256) void proj_kernel(
    const float* __restrict__ x,      // (BN, NN, FIN) fp32
    const float* __restrict__ wproj,  // (D, FIN) fp32
    const float* __restrict__ ssrc,   // (H, FO) fp32
    const float* __restrict__ stgt,   // (H, FO) fp32
    short* __restrict__ pt,           // (nb) PT2 slabs, 1 MiB each
    float* __restrict__ sS,           // (nb*H, NN) fp32
    float* __restrict__ sT,           // (nb*H, NN) fp32
    int b0)
{
    __shared__ short ptl[64][264];    // [f][j_local], +8 pad (33792 B)

    const int tid  = threadIdx.x;
    const int wave = tid >> 6;
    const int lane = tid & 63;
    const int l16  = lane & 15;
    const int quad = lane >> 4;

    const int b_rel = blockIdx.z;
    const int b  = b0 + b_rel;
    const int h  = blockIdx.y;            // head
    const int j0 = blockIdx.x * 256 + wave * 64;

    floatx4 acc[4][4];
#pragma unroll
    for (int mi = 0; mi < 4; ++mi)
#pragma unroll
        for (int nj = 0; nj < 4; ++nj)
            acc[mi][nj] = (floatx4){0.f, 0.f, 0.f, 0.f};

#pragma unroll
    for (int kc = 0; kc < 4; ++kc) {
        const int c = kc * 32 + quad * 8;
        bf16x8 afr[4], bfr[4];
#pragma unroll
        for (int mi = 0; mi < 4; ++mi) {
            int f = mi * 16 + l16;                // f within head
            int srow = f * H_ + h;                // W_proj row (flat d = f*H+h)
            afr[mi] = load8f(wproj + srow * FIN_ + c);
        }
#pragma unroll
        for (int nj = 0; nj < 4; ++nj) {
            int j = j0 + nj * 16 + l16;
            bfr[nj] = load8f(x + ((size_t)b * NN_ + j) * FIN_ + c);
        }
#pragma unroll
        for (int mi = 0; mi < 4; ++mi)
#pragma unroll
            for (int nj = 0; nj < 4; ++nj)
                acc[mi][nj] = __builtin_amdgcn_mfma_f32_16x16x32_bf16(
                    afr[mi], bfr[nj], acc[mi][nj], 0, 0, 0);
    }

    // ---- stage C-fragments into the [f][j_local] LDS tile ----
    // lane holds (f = mi*16 + quad*4 + r, j_local = wave*64 + nj*16 + l16)
#pragma unroll
    for (int mi = 0; mi < 4; ++mi)
#pragma unroll
        for (int r = 0; r < 4; ++r)
#pragma unroll
            for (int nj = 0; nj < 4; ++nj)
                ptl[mi * 16 + quad * 4 + r][wave * 64 + nj * 16 + l16] =
                    f2bf(acc[mi][nj][r]);

    // ---- score dot-products from fp32 accumulators (register-local) ----
    float wsv[4][4], wtv[4][4];
#pragma unroll
    for (int mi = 0; mi < 4; ++mi)
#pragma unroll
        for (int r = 0; r < 4; ++r) {
            int f = mi * 16 + quad * 4 + r;
            wsv[mi][r] = ssrc[h * FO_ + f];
            wtv[mi][r] = stgt[h * FO_ + f];
        }
    const size_t sbase = ((size_t)b_rel * H_ + h) * NN_;
#pragma unroll
    for (int nj = 0; nj < 4; ++nj) {
        float ps = 0.f, pg = 0.f;
#pragma unroll
        for (int mi = 0; mi < 4; ++mi)
#pragma unroll
            for (int r = 0; r < 4; ++r) {
                ps = fmaf(wsv[mi][r], acc[mi][nj][r], ps);
                pg = fmaf(wtv[mi][r], acc[mi][nj][r], pg);
            }
        ps += __shfl_xor(ps, 16, 64); ps += __shfl_xor(ps, 32, 64);
        pg += __shfl_xor(pg, 16, 64); pg += __shfl_xor(pg, 32, 64);
        if (quad == 0) {
            int j = j0 + nj * 16 + l16;
            sS[sbase + j] = ps;
            sT[sbase + j] = pg;
        }
    }

    __syncthreads();

    // ---- dense PT2 store: block's 32 KB range is CONTIGUOUS in PT2 ----
    // unit uid (16B): offset = uid*8 shorts = tile*2048 + mi*512 + l*8
    // holds (f = mi*16 + (l&15), j = tile*32 + (l>>4)*8 + 0..7)
    const size_t base = ((size_t)b_rel * H_ + h) * (size_t)(64 * 2048)
                      + (size_t)(blockIdx.x * 8) * 2048;
#pragma unroll
    for (int p = 0; p < 8; ++p) {
        const int uid  = p * 256 + tid;           // 0..2047
        const int tile = uid >> 8;                // == p (wave-uniform)
        const int mi   = (uid >> 6) & 3;          // == wave
        const int l    = uid & 63;                // == lane
        const int f    = mi * 16 + (l & 15);
        const int js   = tile * 32 + (l >> 4) * 8;
        bf16x8 v = *(const bf16x8*)&ptl[f][js];   // 16B-aligned (264|8, js|8)
        *(bf16x8*)&pt[base + (size_t)uid * 8] = v;  // dense: lane*16B
    }
}

// ---------------------------------------------------------------------------
// Kernel 2: fused attention, 4 heads per block, i-tile = 16.
// UNCHANGED from rounds 6/7 (54.5 us, verified): all main-loop global loads
// dense; adj staged via wave-private LDS tile with T14 issue-early/
// write-late split; PT B-fragments read from PT2 as uniform_base + lane*16.
// ---------------------------------------------------------------------------
#define RSTRIDE 65   // LDS row stride (pad +1 col to break bank alignment)
#define WSLOT   (RSTRIDE * 16 + 16)   // 1056 floats per wave slot

__global__ __launch_bounds__(512, 2) void attn_kernel(
    const float* __restrict__ adj,    // (BN, NN, NN) fp32
    const short* __restrict__ pt,     // PT2 slabs (see proj_kernel)
    const float* __restrict__ sS,     // (nb*H, NN) fp32
    const float* __restrict__ sT,     // (nb*H, NN) fp32
    const float* __restrict__ bias,   // (D,) fp32
    float* __restrict__ out,          // (BN, NN, D) fp32
    int b0)
{
    __shared__ union {
        struct {
            float adjs[8][16][36];    // per-wave adj tile (18432 B)
            float st[8][4][256];      // per-wave s_tgt slices (32768 B)
        } m;
        float red[8][WSLOT];          // cross-wave reduction (33792 B)
    } sm;

    const int tid  = threadIdx.x;
    const int w    = tid >> 6;        // wave = 256-wide j-slice
    const int lane = tid & 63;
    const int l16  = lane & 15;
    const int quad = lane >> 4;
    const int r8   = lane >> 3;       // 0..7  (adj stage row-in-group)
    const int c4   = (lane & 7) * 4;  // 0,4..28 (adj stage col, floats)

    const int b_rel = blockIdx.z;
    const int b  = b0 + b_rel;
    const int i0 = blockIdx.x * 16;

    const short* pt2_b = pt + (size_t)b_rel * H_ * (size_t)(64 * 2048);
    const size_t sb = (size_t)b_rel * H_ * NN_;

    // stage s_tgt slices for all 4 heads (wave-private; no barrier needed)
    {
        const int t = lane * 4;
#pragma unroll
        for (int h = 0; h < 4; ++h)
            *(floatx4*)&sm.m.st[w][h][t] =
                *(const floatx4*)&sT[sb + (size_t)h * NN_ + w * 256 + t];
    }

    // per-lane s_src for my i-row (row = l16), all heads
    float ssv[4];
#pragma unroll
    for (int h = 0; h < 4; ++h)
        ssv[h] = sS[sb + (size_t)h * NN_ + i0 + l16];

    // adj stage base: rows i0.., cols w*256..
    const float* adj_base = adj + ((size_t)b * NN_ + i0) * NN_ + w * 256;

    floatx4 acc[4][4];                // [head][f-block], 64 regs
#pragma unroll
    for (int h = 0; h < 4; ++h)
#pragma unroll
        for (int K = 0; K < 4; ++K)
            acc[h][K] = (floatx4){0.f, 0.f, 0.f, 0.f};
    float ls[4] = {0.f, 0.f, 0.f, 0.f};

    // prologue: dense-load + stage adj tile jt=0
    floatx4 areg0 = *(const floatx4*)(adj_base + (size_t)r8 * NN_ + c4);
    floatx4 areg1 = *(const floatx4*)(adj_base + (size_t)(8 + r8) * NN_ + c4);
    *(floatx4*)&sm.m.adjs[w][r8][c4]     = areg0;
    *(floatx4*)&sm.m.adjs[w][8 + r8][c4] = areg1;

    const int lo8 = lane * 8;         // PT2 per-lane element offset

#pragma unroll
    for (int jt = 0; jt < 8; ++jt) {              // 8 iters x 32 j per wave
        const int o  = jt * 32;                   // static element offset
        const int qo = quad * 8;

        // T14 issue-early: dense global loads for the NEXT adj tile
        if (jt < 7) {
            areg0 = *(const floatx4*)(adj_base + (size_t)r8 * NN_ + o + 32 + c4);
            areg1 = *(const floatx4*)(adj_base + (size_t)(8 + r8) * NN_ + o + 32 + c4);
        }

        // A-values for this tile from LDS (wave-private, already staged)
        floatx4 ajA = *(const floatx4*)&sm.m.adjs[w][l16][qo];
        floatx4 ajB = *(const floatx4*)&sm.m.adjs[w][l16][qo + 4];

#pragma unroll
        for (int u = 0; u < 4; ++u) {
            // dense 1 KB fragment loads from PT2 (uniform base + lane*16B)
            const short* fb = pt2_b + ((size_t)u * 64 + (w * 8 + jt)) * 2048 + lo8;
            bf16x8 bfr[4];
#pragma unroll
            for (int K = 0; K < 4; ++K)
                bfr[K] = *(const bf16x8*)(fb + K * 512);

            const float* stp = &sm.m.st[w][u][qo];
            floatx4 stA = *(const floatx4*)(stp + o);
            floatx4 stB = *(const floatx4*)(stp + o + 4);

            float w0 = score_exp(ssv[u], stA[0], ajA[0]);
            float w1 = score_exp(ssv[u], stA[1], ajA[1]);
            float w2 = score_exp(ssv[u], stA[2], ajA[2]);
            float w3 = score_exp(ssv[u], stA[3], ajA[3]);
            float w4 = score_exp(ssv[u], stB[0], ajB[0]);
            float w5 = score_exp(ssv[u], stB[1], ajB[1]);
            float w6 = score_exp(ssv[u], stB[2], ajB[2]);
            float w7 = score_exp(ssv[u], stB[3], ajB[3]);
            ls[u] += ((w0 + w1) + (w2 + w3)) + ((w4 + w5) + (w6 + w7));
            union { bf16x8 v; unsigned int u4[4]; } a0;
            a0.u4[0] = pack_bf16(w0, w1);
            a0.u4[1] = pack_bf16(w2, w3);
            a0.u4[2] = pack_bf16(w4, w5);
            a0.u4[3] = pack_bf16(w6, w7);
#pragma unroll
            for (int K = 0; K < 4; ++K)
                acc[u][K] = __builtin_amdgcn_mfma_f32_16x16x32_bf16(
                    a0.v, bfr[K], acc[u][K], 0, 0, 0);
        }

        // T14 write-late: stage next tile after this tile's LDS reads
        if (jt < 7) {
            *(floatx4*)&sm.m.adjs[w][r8][c4]     = areg0;
            *(floatx4*)&sm.m.adjs[w][8 + r8][c4] = areg1;
        }
    }

    // wave-local row-sums over quads (row = l16 in A-layout)
#pragma unroll
    for (int h = 0; h < 4; ++h) {
        ls[h] += __shfl_xor(ls[h], 16, 64);
        ls[h] += __shfl_xor(ls[h], 32, 64);
    }

    // epilogue: 4 head-chunks of 16 rows; 8-wave LDS reduction per chunk
#pragma unroll
    for (int h = 0; h < 4; ++h) {
        __syncthreads();   // h=0: all main-loop LDS reads done; h>0: prev chunk
#pragma unroll
        for (int K = 0; K < 4; ++K)
#pragma unroll
            for (int r = 0; r < 4; ++r)
                sm.red[w][(quad * 4 + r) * RSTRIDE + K * 16 + l16] = acc[h][K][r];
        if (quad == 0)
            sm.red[w][16 * RSTRIDE + l16] = ls[h];
        __syncthreads();
#pragma unroll
        for (int p = 0; p < 2; ++p) {
            int e   = tid + p * 512;
            int row = e >> 6;
            int col = e & 63;
            float s = 0.f, l = 0.f;
#pragma unroll
            for (int ww = 0; ww < 8; ++ww) {
                s += sm.red[ww][row * RSTRIDE + col];
                l += sm.red[ww][16 * RSTRIDE + row];
            }
            float v = s / l + bias[h * FO_ + col];
            v = (v > 0.f) ? v : expm1f(v);        // elu (fp32 out)
            out[((size_t)b * NN_ + i0 + row) * D_ + h * FO_ + col] = v;
        }
    }
}

// ---------------------------------------------------------------------------
extern "C" void kernel_launch(void* const* d_in, const int* in_sizes, int n_in,
                              void* d_out, int out_size, void* d_ws, size_t ws_size,
                              hipStream_t stream) {
    const float* x     = (const float*)d_in[0];   // (4,2048,128) fp32
    const float* adj   = (const float*)d_in[1];   // (4,2048,2048) fp32
    const float* wproj = (const float*)d_in[2];   // (256,128) fp32
    const float* ssrc  = (const float*)d_in[3];   // (4,64) fp32
    const float* stgt  = (const float*)d_in[4];   // (4,64) fp32
    const float* bias  = (const float*)d_in[5];   // (256,) fp32
    float* out = (float*)d_out;                   // (4,2048,256) fp32

    // ws layout per batch: PT2 slab (1 MiB) + s_src/s_tgt (64 KiB)
    const size_t SLAB  = (size_t)D_ * NN_ * 2;          // bf16 PT2
    const size_t SSLAB = (size_t)2 * H_ * NN_ * 4;      // fp32 sS+sT
    int nb = (int)(ws_size / (SLAB + SSLAB));
    if (nb < 1) nb = 1;
    if (nb > 4) nb = 4;

    short* pt = (short*)d_ws;
    float* sv = (float*)((char*)d_ws + (size_t)nb * SLAB);
    float* sS = sv;
    float* sT = sv + (size_t)nb * H_ * NN_;

    for (int bb0 = 0; bb0 < BN_; bb0 += nb) {
        int cnt = (BN_ - bb0 < nb) ? (BN_ - bb0) : nb;
        proj_kernel<<<dim3(NN_ / 256, H_, cnt), 256, 0, stream>>>(
            x, wproj, ssrc, stgt, pt, sS, sT, bb0);
        attn_kernel<<<dim3(NN_ / 16, 1, cnt), 512, 0, stream>>>(
            adj, pt, sS, sT, bias, out, bb0);
    }
}